// Round 14
// baseline (531.236 us; speedup 1.0000x reference)
//
#include <hip/hip_runtime.h>

// ---------------------------------------------------------------------------
// 3-layer GCN (PyG gcn_norm semantics) on MI355X.
// R14 = R13 with gemm1 restructured BARRIER-FREE:
//   - 64-thread blocks (1 wave) with a 32x64 output tile each; grid 2048.
//   - wave stages its own 32x32 fp32 A panel (coalesced, NT), converts
//     (cvt_pk), transposes through wave-PRIVATE LDS (5KB, lgkmcnt-only
//     hazards, NO s_barrier at all) -> loads stay in flight continuously.
//   - B hi/lo fragments from global (L2-resident per XCD, K-chunk swizzle).
// Also: scan_top fused into scan_add (one fewer dispatch).
// Tail otherwise identical to R13 (fused prop64+gemm2, prop32+gemm3, etc).
// ---------------------------------------------------------------------------

typedef __attribute__((ext_vector_type(8))) short bf16x8;
typedef __attribute__((ext_vector_type(4))) float f32x4;
typedef __attribute__((ext_vector_type(4))) float fv4;

__device__ __forceinline__ float4 ldnt4(const float* p) {
    fv4 v = __builtin_nontemporal_load((const fv4*)p);
    return make_float4(v.x, v.y, v.z, v.w);
}
__device__ __forceinline__ void stnt(float* p, float v) {
    __builtin_nontemporal_store(v, p);
}

__device__ __forceinline__ unsigned cvt_pk_bf16(float a, float b) {
    // D[15:0] = bf16_rne(a), D[31:16] = bf16_rne(b)
    unsigned r;
    asm("v_cvt_pk_bf16_f32 %0, %1, %2" : "=v"(r) : "v"(a), "v"(b));
    return r;
}

__device__ __forceinline__ unsigned short f2bf_rne(float f) {
    unsigned u = __float_as_uint(f);
    unsigned r = (u + 0x7FFFu + ((u >> 16) & 1u)) >> 16;
    return (unsigned short)r;
}

// --- fused: zero cnt + int64-vs-int32 probe + W1 split/transpose
__global__ void init_prep_k(const int* __restrict__ ei, int* __restrict__ flag,
                            int* __restrict__ cnt, int n,
                            const float* __restrict__ W1,
                            unsigned short* __restrict__ Bt, int K) {
    int t = blockIdx.x * blockDim.x + threadIdx.x;
    if (t < n) cnt[t] = 0;
    if (t == 0) {
        int f = 1;
        for (int i = 0; i < 256; ++i) {
            if (ei[2 * i + 1] != 0) { f = 0; break; }
        }
        *flag = f;
    }
    if (t < K * 64) {
        int nn = t & 63, k = t >> 6;
        float f = W1[(size_t)k * 64 + nn];
        unsigned short hi = f2bf_rne(f);
        float hf = __uint_as_float((unsigned)hi << 16);
        unsigned short lo = f2bf_rne(f - hf);
        Bt[(size_t)nn * K + k] = hi;
        Bt[(size_t)64 * K + (size_t)nn * K + k] = lo;
    }
}

__device__ __forceinline__ int edge_val(const int* __restrict__ ei, long long idx, int f64) {
    return f64 ? ei[2 * idx] : ei[(int)idx];
}

__global__ void count_deg_k(const int* __restrict__ ei, int E, const int* __restrict__ flag,
                            int* __restrict__ cnt) {
    int e = blockIdx.x * blockDim.x + threadIdx.x;
    if (e >= E) return;
    int f = *flag;
    int c = edge_val(ei, (long long)E + e, f);
    atomicAdd(&cnt[c], 1);
}

// --- multi-block scan, phase A: per-block local exclusive scan + totals
//     + dis = rsqrt(deg+1) + cursor = 0.
__global__ void scan_blk_k(const int* __restrict__ cnt, int* __restrict__ offs,
                           float* __restrict__ dis, int* __restrict__ cursor,
                           int* __restrict__ btot, int n) {
    __shared__ int sh[256];
    const int t = threadIdx.x;
    const int idx = blockIdx.x * 256 + t;
    int v = (idx < n) ? cnt[idx] : 0;
    sh[t] = v;
    __syncthreads();
    for (int o = 1; o < 256; o <<= 1) {
        int add = (t >= o) ? sh[t - o] : 0;
        __syncthreads();
        sh[t] += add;
        __syncthreads();
    }
    if (idx < n) {
        offs[idx] = sh[t] - v;  // exclusive local prefix
        cursor[idx] = 0;
        dis[idx] = rsqrtf((float)(v + 1));  // +1: self loop
    }
    if (t == 255) btot[blockIdx.x] = sh[255];
}

// phase B (fused top-scan + add): each block derives its base from btot.
__global__ void scan_add_k(int* __restrict__ offs, const int* __restrict__ btot,
                           int n, int nb) {
    __shared__ int base_sh, tot_sh;
    const int t = threadIdx.x;
    if (t == 0) {
        int base = 0, tot = 0;
        for (int i = 0; i < nb; ++i) {
            int v = btot[i];
            if (i < (int)blockIdx.x) base += v;
            tot += v;
        }
        base_sh = base;
        tot_sh = tot;
    }
    __syncthreads();
    int idx = blockIdx.x * 256 + t;
    if (idx < n) offs[idx] += base_sh;
    if (blockIdx.x == 0 && t == 0) offs[n] = tot_sh;
}

__global__ void fill_csr_k(const int* __restrict__ ei, int E, const int* __restrict__ flag,
                           const int* __restrict__ offs, int* __restrict__ cursor,
                           const float* __restrict__ dis, int* __restrict__ src,
                           float* __restrict__ w) {
    int e = blockIdx.x * blockDim.x + threadIdx.x;
    if (e >= E) return;
    int f = *flag;
    int r = edge_val(ei, (long long)e, f);
    int c = edge_val(ei, (long long)E + e, f);
    int pos = offs[c] + atomicAdd(&cursor[c], 1);
    src[pos] = r;
    w[pos] = dis[r] * dis[c];
}

// --- GEMM1 v2: [n x K] fp32 @ Bt[2][64][K] -> P[kz][n][64], split-bf16 MFMA.
// ONE WAVE PER BLOCK (64 thr), tile 32x64, K-split x4, NO barriers:
// wave-private LDS transpose with lgkmcnt-only hazards; loads never drain.
__global__ __launch_bounds__(64) void gemm1_mfma_k(
    const float* __restrict__ A, const unsigned short* __restrict__ Bt,
    float* __restrict__ P, int n, int K, int kchunk) {
    __shared__ unsigned short As[2][32][40];  // [hi/lo][row][k], pad 40; 5KB
    const int lane = threadIdx.x;
    const int lrow = lane & 15, lkh = lane >> 4;
    // XCD-grouped swizzle: XCD pair {2y,2y+1} owns K-chunk y -> its 2MB of B
    const int bid = blockIdx.x;
    const int by = (bid & 7) >> 1;
    const int bx = ((bid >> 3) << 1) | (bid & 1);
    const int bm = bx * 32;
    const int k0 = by * kchunk;
    const int iters = kchunk / 32;  // K=16384 /4 /32 = 128

    const unsigned short* Bh = Bt;
    const unsigned short* Bl = Bt + (size_t)64 * K;

    f32x4 acc[2][4] = {};
    float4 st[4];

    auto loadA = [&](int kt) {
#pragma unroll
        for (int i = 0; i < 4; ++i) {
            int v = lane + i * 64;
            int r = v >> 3, c = (v & 7) * 4;
            st[i] = ldnt4(A + (size_t)(bm + r) * K + k0 + kt * 32 + c);
        }
    };

    loadA(0);
    for (int kt = 0; kt < iters; ++kt) {
        // B fragments (full 64 cols) from global -- L2-resident, NOT nt
        bf16x8 bh[4], bl[4];
#pragma unroll
        for (int nf = 0; nf < 4; ++nf) {
            int brow = nf * 16 + lrow;
            size_t bo = (size_t)brow * K + k0 + kt * 32 + lkh * 8;
            bh[nf] = *(const bf16x8*)(Bh + bo);
            bl[nf] = *(const bf16x8*)(Bl + bo);
        }
        // convert staged A regs -> hi/lo bf16 -> wave-private LDS
#pragma unroll
        for (int i = 0; i < 4; ++i) {
            int v = lane + i * 64;
            int r = v >> 3, c = (v & 7) * 4;
            float f0 = st[i].x, f1 = st[i].y, f2 = st[i].z, f3 = st[i].w;
            unsigned h01 = cvt_pk_bf16(f0, f1);
            unsigned h23 = cvt_pk_bf16(f2, f3);
            float r0 = f0 - __uint_as_float(h01 << 16);
            float r1 = f1 - __uint_as_float(h01 & 0xFFFF0000u);
            float r2 = f2 - __uint_as_float(h23 << 16);
            float r3 = f3 - __uint_as_float(h23 & 0xFFFF0000u);
            unsigned l01 = cvt_pk_bf16(r0, r1);
            unsigned l23 = cvt_pk_bf16(r2, r3);
            *(uint2*)&As[0][r][c] = make_uint2(h01, h23);
            *(uint2*)&As[1][r][c] = make_uint2(l01, l23);
        }
        if (kt + 1 < iters) loadA(kt + 1);  // prefetch; stays in flight
        // wave-synchronous LDS read (compiler inserts lgkmcnt, no barrier)
        bf16x8 ah[2], al[2];
#pragma unroll
        for (int mf = 0; mf < 2; ++mf) {
            int row = mf * 16 + lrow;
            ah[mf] = *(const bf16x8*)&As[0][row][lkh * 8];
            al[mf] = *(const bf16x8*)&As[1][row][lkh * 8];
        }
#pragma unroll
        for (int mf = 0; mf < 2; ++mf)
#pragma unroll
            for (int nf = 0; nf < 4; ++nf) {
                acc[mf][nf] = __builtin_amdgcn_mfma_f32_16x16x32_bf16(ah[mf], bh[nf], acc[mf][nf], 0, 0, 0);
                acc[mf][nf] = __builtin_amdgcn_mfma_f32_16x16x32_bf16(al[mf], bh[nf], acc[mf][nf], 0, 0, 0);
                acc[mf][nf] = __builtin_amdgcn_mfma_f32_16x16x32_bf16(ah[mf], bl[nf], acc[mf][nf], 0, 0, 0);
            }
    }
    // C/D layout: col = lane&15, row = (lane>>4)*4 + reg. NT stores.
    float* out = P + (size_t)by * n * 64;
#pragma unroll
    for (int mf = 0; mf < 2; ++mf)
#pragma unroll
        for (int nf = 0; nf < 4; ++nf)
#pragma unroll
            for (int j = 0; j < 4; ++j) {
                int row = bm + mf * 16 + lkh * 4 + j;
                int col = nf * 16 + lrow;
                stnt(out + (size_t)row * 64 + col, acc[mf][nf][j]);
            }
}

__global__ void reduce4_k(float4* __restrict__ p, size_t q) {
    size_t i = (size_t)blockIdx.x * blockDim.x + threadIdx.x;
    if (i >= q) return;
    float4 a = p[i];
#pragma unroll
    for (int z = 1; z < 4; ++z) {
        float4 b = ldnt4((const float*)(p + i + (size_t)z * q));
        a.x += b.x; a.y += b.y; a.z += b.z; a.w += b.w;
    }
    p[i] = a;
}

// --- fused: H1 = relu(Agg(H0)+b1) ; H2a = H1 @ W2.  16 thr/node, 16 nodes/blk.
__global__ __launch_bounds__(256) void prop64_gemm2_k(
    const float* __restrict__ h, const int* __restrict__ offs,
    const int* __restrict__ src, const float* __restrict__ w,
    const float* __restrict__ dis, const float* __restrict__ b1,
    const float* __restrict__ W2, float* __restrict__ H2a, int n) {
    __shared__ float Ws[64 * 32];
    __shared__ float rows[16][68];  // pad 68
    const int tid = threadIdx.x;
    for (int i = tid; i < 64 * 32; i += 256) Ws[i] = W2[i];
    const int t = blockIdx.x * 256 + tid;
    const int node = t >> 4, q = t & 15, nl = tid >> 4;
    float4 acc = make_float4(0.f, 0.f, 0.f, 0.f);
    int p0 = offs[node], p1 = offs[node + 1];
    for (int p = p0; p < p1; ++p) {
        float ww = w[p];
        float4 hv = *(const float4*)(h + (size_t)src[p] * 64 + q * 4);
        acc.x = fmaf(ww, hv.x, acc.x);
        acc.y = fmaf(ww, hv.y, acc.y);
        acc.z = fmaf(ww, hv.z, acc.z);
        acc.w = fmaf(ww, hv.w, acc.w);
    }
    float d = dis[node];
    float ds = d * d;
    float4 hv = *(const float4*)(h + (size_t)node * 64 + q * 4);
    float4 bv = *(const float4*)(b1 + q * 4);
    acc.x = fmaxf(fmaf(ds, hv.x, acc.x) + bv.x, 0.f);
    acc.y = fmaxf(fmaf(ds, hv.y, acc.y) + bv.y, 0.f);
    acc.z = fmaxf(fmaf(ds, hv.z, acc.z) + bv.z, 0.f);
    acc.w = fmaxf(fmaf(ds, hv.w, acc.w) + bv.w, 0.f);
    *(float4*)&rows[nl][q * 4] = acc;
    __syncthreads();
    const int c0 = q * 2;
    float s0 = 0.f, s1 = 0.f;
#pragma unroll
    for (int k = 0; k < 64; ++k) {
        float v = rows[nl][k];
        s0 = fmaf(v, Ws[k * 32 + c0], s0);
        s1 = fmaf(v, Ws[k * 32 + c0 + 1], s1);
    }
    H2a[(size_t)node * 32 + c0] = s0;
    H2a[(size_t)node * 32 + c0 + 1] = s1;
}

// --- fused: H2 = relu(Agg(H2a)+b2) ; H3a = H2 @ W3.  8 thr/node, 32 nodes/blk.
__global__ __launch_bounds__(256) void prop32_gemm3_k(
    const float* __restrict__ h, const int* __restrict__ offs,
    const int* __restrict__ src, const float* __restrict__ w,
    const float* __restrict__ dis, const float* __restrict__ b2,
    const float* __restrict__ W3, float* __restrict__ H3a, int n) {
    __shared__ float Ws[32 * 16];
    __shared__ float rows[32][36];  // pad 36
    const int tid = threadIdx.x;
    for (int i = tid; i < 32 * 16; i += 256) Ws[i] = W3[i];
    const int t = blockIdx.x * 256 + tid;
    const int node = t >> 3, q = t & 7, nl = tid >> 3;
    float4 acc = make_float4(0.f, 0.f, 0.f, 0.f);
    int p0 = offs[node], p1 = offs[node + 1];
    for (int p = p0; p < p1; ++p) {
        float ww = w[p];
        float4 hv = *(const float4*)(h + (size_t)src[p] * 32 + q * 4);
        acc.x = fmaf(ww, hv.x, acc.x);
        acc.y = fmaf(ww, hv.y, acc.y);
        acc.z = fmaf(ww, hv.z, acc.z);
        acc.w = fmaf(ww, hv.w, acc.w);
    }
    float d = dis[node];
    float ds = d * d;
    float4 hv = *(const float4*)(h + (size_t)node * 32 + q * 4);
    float4 bv = *(const float4*)(b2 + q * 4);
    acc.x = fmaxf(fmaf(ds, hv.x, acc.x) + bv.x, 0.f);
    acc.y = fmaxf(fmaf(ds, hv.y, acc.y) + bv.y, 0.f);
    acc.z = fmaxf(fmaf(ds, hv.z, acc.z) + bv.z, 0.f);
    acc.w = fmaxf(fmaf(ds, hv.w, acc.w) + bv.w, 0.f);
    *(float4*)&rows[nl][q * 4] = acc;
    __syncthreads();
    const int c0 = q * 2;
    float s0 = 0.f, s1 = 0.f;
#pragma unroll
    for (int k = 0; k < 32; ++k) {
        float v = rows[nl][k];
        s0 = fmaf(v, Ws[k * 16 + c0], s0);
        s1 = fmaf(v, Ws[k * 16 + c0 + 1], s1);
    }
    H3a[(size_t)node * 16 + c0] = s0;
    H3a[(size_t)node * 16 + c0 + 1] = s1;
}

// --- final propagate (F=16) + bias + softmax, float4/thread, 4 lanes/node
__global__ void prop_softmax_k(const float* __restrict__ h, const int* __restrict__ offs,
                               const int* __restrict__ src, const float* __restrict__ w,
                               const float* __restrict__ dis, const float* __restrict__ b,
                               float* __restrict__ out, int n) {
    int t = blockIdx.x * blockDim.x + threadIdx.x;
    int node = t >> 2, q = t & 3;
    if (node >= n) return;
    float4 acc = make_float4(0.f, 0.f, 0.f, 0.f);
    int p0 = offs[node], p1 = offs[node + 1];
    for (int p = p0; p < p1; ++p) {
        float ww = w[p];
        float4 hv = *(const float4*)(h + (size_t)src[p] * 16 + q * 4);
        acc.x = fmaf(ww, hv.x, acc.x);
        acc.y = fmaf(ww, hv.y, acc.y);
        acc.z = fmaf(ww, hv.z, acc.z);
        acc.w = fmaf(ww, hv.w, acc.w);
    }
    float d = dis[node];
    float ds = d * d;
    float4 hv = *(const float4*)(h + (size_t)node * 16 + q * 4);
    float4 bv = *(const float4*)(b + q * 4);
    acc.x = fmaf(ds, hv.x, acc.x) + bv.x;
    acc.y = fmaf(ds, hv.y, acc.y) + bv.y;
    acc.z = fmaf(ds, hv.z, acc.z) + bv.z;
    acc.w = fmaf(ds, hv.w, acc.w) + bv.w;
    float m = fmaxf(fmaxf(acc.x, acc.y), fmaxf(acc.z, acc.w));
    m = fmaxf(m, __shfl_xor(m, 1));
    m = fmaxf(m, __shfl_xor(m, 2));
    float4 e;
    e.x = __expf(acc.x - m);
    e.y = __expf(acc.y - m);
    e.z = __expf(acc.z - m);
    e.w = __expf(acc.w - m);
    float s = e.x + e.y + e.z + e.w;
    s += __shfl_xor(s, 1);
    s += __shfl_xor(s, 2);
    float inv = 1.f / s;
    e.x *= inv; e.y *= inv; e.z *= inv; e.w *= inv;
    *(float4*)(out + (size_t)node * 16 + q * 4) = e;
}

extern "C" void kernel_launch(void* const* d_in, const int* in_sizes, int n_in,
                              void* d_out, int out_size, void* d_ws, size_t ws_size,
                              hipStream_t stream) {
    const float* x  = (const float*)d_in[0];
    const int*   ei = (const int*)d_in[1];
    const float* W1 = (const float*)d_in[2];
    const float* b1 = (const float*)d_in[3];
    const float* W2 = (const float*)d_in[4];
    const float* b2 = (const float*)d_in[5];
    const float* W3 = (const float*)d_in[6];
    const float* b3 = (const float*)d_in[7];
    float* out = (float*)d_out;

    const int n = in_sizes[2] / 64;
    const int K = in_sizes[0] / n;
    const int E = in_sizes[1] / 2;
    const int nb = (n + 255) / 256;  // scan blocks (64 for n=16384)

    char* ws = (char*)d_ws;
    size_t off = 0;
    auto alloc = [&](size_t bytes) {
        char* p = ws + off;
        off = (off + bytes + 255) & ~(size_t)255;
        return p;
    };
    int*   flag   = (int*)  alloc(4);
    int*   cnt    = (int*)  alloc((size_t)n * 4);
    int*   cursor = (int*)  alloc((size_t)n * 4);
    int*   offs   = (int*)  alloc((size_t)(n + 1) * 4);
    int*   btot   = (int*)  alloc((size_t)nb * 4);
    float* dis    = (float*)alloc((size_t)n * 4);
    int*   csrs   = (int*)  alloc((size_t)E * 4);
    float* csrw   = (float*)alloc((size_t)E * 4);
    unsigned short* Btw = (unsigned short*)alloc((size_t)2 * 64 * K * 2);
    float* P      = (float*)alloc((size_t)4 * n * 64 * 4);  // partials; plane 0 = H0
    float* H2a    = (float*)alloc((size_t)n * 32 * 4);
    float* H3a    = (float*)alloc((size_t)n * 16 * 4);
    (void)ws_size; (void)n_in; (void)out_size;

    init_prep_k<<<(K * 64 + 255) / 256, 256, 0, stream>>>(ei, flag, cnt, n, W1, Btw, K);
    count_deg_k<<<(E + 255) / 256, 256, 0, stream>>>(ei, E, flag, cnt);
    scan_blk_k<<<nb, 256, 0, stream>>>(cnt, offs, dis, cursor, btot, n);
    scan_add_k<<<nb, 256, 0, stream>>>(offs, btot, n, nb);
    fill_csr_k<<<(E + 255) / 256, 256, 0, stream>>>(ei, E, flag, offs, cursor, dis, csrs, csrw);

    gemm1_mfma_k<<<(n / 32) * 4, 64, 0, stream>>>(x, Btw, P, n, K, K / 4);
    size_t q = (size_t)n * 64 / 4;
    reduce4_k<<<(int)((q + 255) / 256), 256, 0, stream>>>((float4*)P, q);

    prop64_gemm2_k<<<n * 16 / 256, 256, 0, stream>>>(P, offs, csrs, csrw, dis, b1, W2, H2a, n);
    prop32_gemm3_k<<<n * 8 / 256, 256, 0, stream>>>(H2a, offs, csrs, csrw, dis, b2, W3, H3a, n);
    prop_softmax_k<<<n * 4 / 256, 256, 0, stream>>>(H3a, offs, csrs, csrw, dis, b3, out, n);
}

// Round 15
// 382.273 us; speedup vs baseline: 1.3897x; 1.3897x over previous
//
#include <hip/hip_runtime.h>

// ---------------------------------------------------------------------------
// 3-layer GCN (PyG gcn_norm semantics) on MI355X.
// R15 = R13 (best, 368us) with two conservative changes:
//   1. gemm1 BK 32->64: same skeleton (BM=128, 4 waves, 2 barriers/step,
//      NT A-loads, cvt_pk, XCD-pair swizzle) but half as many barrier
//      intervals with twice the work each -> barrier-sync cost halves.
//   2. scan_add with inlined top-scan (from R14, verified) -> -1 dispatch.
// Tail otherwise identical to R13.
// ---------------------------------------------------------------------------

typedef __attribute__((ext_vector_type(8))) short bf16x8;
typedef __attribute__((ext_vector_type(4))) float f32x4;
typedef __attribute__((ext_vector_type(4))) float fv4;

__device__ __forceinline__ float4 ldnt4(const float* p) {
    fv4 v = __builtin_nontemporal_load((const fv4*)p);
    return make_float4(v.x, v.y, v.z, v.w);
}
__device__ __forceinline__ void stnt(float* p, float v) {
    __builtin_nontemporal_store(v, p);
}

__device__ __forceinline__ unsigned cvt_pk_bf16(float a, float b) {
    // D[15:0] = bf16_rne(a), D[31:16] = bf16_rne(b)
    unsigned r;
    asm("v_cvt_pk_bf16_f32 %0, %1, %2" : "=v"(r) : "v"(a), "v"(b));
    return r;
}

__device__ __forceinline__ unsigned short f2bf_rne(float f) {
    unsigned u = __float_as_uint(f);
    unsigned r = (u + 0x7FFFu + ((u >> 16) & 1u)) >> 16;
    return (unsigned short)r;
}

// --- fused: zero cnt + int64-vs-int32 probe + W1 split/transpose
__global__ void init_prep_k(const int* __restrict__ ei, int* __restrict__ flag,
                            int* __restrict__ cnt, int n,
                            const float* __restrict__ W1,
                            unsigned short* __restrict__ Bt, int K) {
    int t = blockIdx.x * blockDim.x + threadIdx.x;
    if (t < n) cnt[t] = 0;
    if (t == 0) {
        int f = 1;
        for (int i = 0; i < 256; ++i) {
            if (ei[2 * i + 1] != 0) { f = 0; break; }
        }
        *flag = f;
    }
    if (t < K * 64) {
        int nn = t & 63, k = t >> 6;
        float f = W1[(size_t)k * 64 + nn];
        unsigned short hi = f2bf_rne(f);
        float hf = __uint_as_float((unsigned)hi << 16);
        unsigned short lo = f2bf_rne(f - hf);
        Bt[(size_t)nn * K + k] = hi;
        Bt[(size_t)64 * K + (size_t)nn * K + k] = lo;
    }
}

__device__ __forceinline__ int edge_val(const int* __restrict__ ei, long long idx, int f64) {
    return f64 ? ei[2 * idx] : ei[(int)idx];
}

__global__ void count_deg_k(const int* __restrict__ ei, int E, const int* __restrict__ flag,
                            int* __restrict__ cnt) {
    int e = blockIdx.x * blockDim.x + threadIdx.x;
    if (e >= E) return;
    int f = *flag;
    int c = edge_val(ei, (long long)E + e, f);
    atomicAdd(&cnt[c], 1);
}

// --- multi-block scan, phase A: per-block local exclusive scan + totals
//     + dis = rsqrt(deg+1) + cursor = 0.
__global__ void scan_blk_k(const int* __restrict__ cnt, int* __restrict__ offs,
                           float* __restrict__ dis, int* __restrict__ cursor,
                           int* __restrict__ btot, int n) {
    __shared__ int sh[256];
    const int t = threadIdx.x;
    const int idx = blockIdx.x * 256 + t;
    int v = (idx < n) ? cnt[idx] : 0;
    sh[t] = v;
    __syncthreads();
    for (int o = 1; o < 256; o <<= 1) {
        int add = (t >= o) ? sh[t - o] : 0;
        __syncthreads();
        sh[t] += add;
        __syncthreads();
    }
    if (idx < n) {
        offs[idx] = sh[t] - v;  // exclusive local prefix
        cursor[idx] = 0;
        dis[idx] = rsqrtf((float)(v + 1));  // +1: self loop
    }
    if (t == 255) btot[blockIdx.x] = sh[255];
}

// phase B (fused top-scan + add): each block derives its base from btot.
__global__ void scan_add_k(int* __restrict__ offs, const int* __restrict__ btot,
                           int n, int nb) {
    __shared__ int base_sh, tot_sh;
    const int t = threadIdx.x;
    if (t == 0) {
        int base = 0, tot = 0;
        for (int i = 0; i < nb; ++i) {
            int v = btot[i];
            if (i < (int)blockIdx.x) base += v;
            tot += v;
        }
        base_sh = base;
        tot_sh = tot;
    }
    __syncthreads();
    int idx = blockIdx.x * 256 + t;
    if (idx < n) offs[idx] += base_sh;
    if (blockIdx.x == 0 && t == 0) offs[n] = tot_sh;
}

__global__ void fill_csr_k(const int* __restrict__ ei, int E, const int* __restrict__ flag,
                           const int* __restrict__ offs, int* __restrict__ cursor,
                           const float* __restrict__ dis, int* __restrict__ src,
                           float* __restrict__ w) {
    int e = blockIdx.x * blockDim.x + threadIdx.x;
    if (e >= E) return;
    int f = *flag;
    int r = edge_val(ei, (long long)e, f);
    int c = edge_val(ei, (long long)E + e, f);
    int pos = offs[c] + atomicAdd(&cursor[c], 1);
    src[pos] = r;
    w[pos] = dis[r] * dis[c];
}

// --- GEMM1: [n x K] fp32 @ Bt[2][64][K] -> P[kz][n][64], split-bf16 MFMA.
// BM=128, BN=64, BK=64, 256 thr = 4 waves (2m x 2n), wave tile 64x32.
// K-split x4 (grid 512). Same 2-barrier skeleton as R5/R13; 64 K-steps.
__global__ __launch_bounds__(256) void gemm1_mfma_k(
    const float* __restrict__ A, const unsigned short* __restrict__ Bt,
    float* __restrict__ P, int n, int K, int kchunk) {
    __shared__ unsigned short As[2][128][72];  // [hi/lo][row][k0..63], pad 72
    const int tid = threadIdx.x;
    const int lane = tid & 63;
    const int wid = tid >> 6;
    const int wm = wid >> 1, wn = wid & 1;
    const int lrow = lane & 15, lkh = lane >> 4;
    // XCD-grouped swizzle: XCD pair {2y,2y+1} owns K-chunk y -> its 2MB of B
    const int bid = blockIdx.x;
    const int by = (bid & 7) >> 1;
    const int bx = ((bid >> 3) << 1) | (bid & 1);
    const int bm = bx * 128;
    const int k0 = by * kchunk;
    const int iters = kchunk / 64;  // K=16384 /4 /64 = 64

    const unsigned short* Bh = Bt;
    const unsigned short* Bl = Bt + (size_t)64 * K;

    f32x4 acc[4][2] = {};
    float4 st[8];

    auto loadA = [&](int kt) {
#pragma unroll
        for (int i = 0; i < 8; ++i) {
            int v = tid + i * 256;
            int r = v >> 4, c = (v & 15) * 4;
            st[i] = ldnt4(A + (size_t)(bm + r) * K + k0 + kt * 64 + c);
        }
    };

    loadA(0);
    for (int kt = 0; kt < iters; ++kt) {
        // B fragments for both k-subtiles (L2-resident; NOT nt)
        bf16x8 bh[2][2], bl[2][2];
#pragma unroll
        for (int ks = 0; ks < 2; ++ks)
#pragma unroll
            for (int nf = 0; nf < 2; ++nf) {
                int brow = wn * 32 + nf * 16 + lrow;
                size_t bo = (size_t)brow * K + k0 + kt * 64 + ks * 32 + lkh * 8;
                bh[ks][nf] = *(const bf16x8*)(Bh + bo);
                bl[ks][nf] = *(const bf16x8*)(Bl + bo);
            }
        // convert staged A regs -> hi/lo bf16 -> LDS (cvt_pk)
#pragma unroll
        for (int i = 0; i < 8; ++i) {
            int v = tid + i * 256;
            int r = v >> 4, c = (v & 15) * 4;
            float f0 = st[i].x, f1 = st[i].y, f2 = st[i].z, f3 = st[i].w;
            unsigned h01 = cvt_pk_bf16(f0, f1);
            unsigned h23 = cvt_pk_bf16(f2, f3);
            float r0 = f0 - __uint_as_float(h01 << 16);
            float r1 = f1 - __uint_as_float(h01 & 0xFFFF0000u);
            float r2 = f2 - __uint_as_float(h23 << 16);
            float r3 = f3 - __uint_as_float(h23 & 0xFFFF0000u);
            unsigned l01 = cvt_pk_bf16(r0, r1);
            unsigned l23 = cvt_pk_bf16(r2, r3);
            *(uint2*)&As[0][r][c] = make_uint2(h01, h23);
            *(uint2*)&As[1][r][c] = make_uint2(l01, l23);
        }
        __syncthreads();
        if (kt + 1 < iters) loadA(kt + 1);  // prefetch under MFMA
#pragma unroll
        for (int ks = 0; ks < 2; ++ks) {
            bf16x8 ah[4], al[4];
#pragma unroll
            for (int mf = 0; mf < 4; ++mf) {
                int row = wm * 64 + mf * 16 + lrow;
                ah[mf] = *(const bf16x8*)&As[0][row][ks * 32 + lkh * 8];
                al[mf] = *(const bf16x8*)&As[1][row][ks * 32 + lkh * 8];
            }
#pragma unroll
            for (int mf = 0; mf < 4; ++mf)
#pragma unroll
                for (int nf = 0; nf < 2; ++nf) {
                    acc[mf][nf] = __builtin_amdgcn_mfma_f32_16x16x32_bf16(ah[mf], bh[ks][nf], acc[mf][nf], 0, 0, 0);
                    acc[mf][nf] = __builtin_amdgcn_mfma_f32_16x16x32_bf16(al[mf], bh[ks][nf], acc[mf][nf], 0, 0, 0);
                    acc[mf][nf] = __builtin_amdgcn_mfma_f32_16x16x32_bf16(ah[mf], bl[ks][nf], acc[mf][nf], 0, 0, 0);
                }
        }
        __syncthreads();
    }
    // C/D layout: col = lane&15, row = (lane>>4)*4 + reg. NT stores.
    float* out = P + (size_t)by * n * 64;
#pragma unroll
    for (int mf = 0; mf < 4; ++mf)
#pragma unroll
        for (int nf = 0; nf < 2; ++nf)
#pragma unroll
            for (int j = 0; j < 4; ++j) {
                int row = bm + wm * 64 + mf * 16 + lkh * 4 + j;
                int col = wn * 32 + nf * 16 + lrow;
                stnt(out + (size_t)row * 64 + col, acc[mf][nf][j]);
            }
}

__global__ void reduce4_k(float4* __restrict__ p, size_t q) {
    size_t i = (size_t)blockIdx.x * blockDim.x + threadIdx.x;
    if (i >= q) return;
    float4 a = p[i];
#pragma unroll
    for (int z = 1; z < 4; ++z) {
        float4 b = ldnt4((const float*)(p + i + (size_t)z * q));
        a.x += b.x; a.y += b.y; a.z += b.z; a.w += b.w;
    }
    p[i] = a;
}

// --- fused: H1 = relu(Agg(H0)+b1) ; H2a = H1 @ W2.  16 thr/node, 16 nodes/blk.
__global__ __launch_bounds__(256) void prop64_gemm2_k(
    const float* __restrict__ h, const int* __restrict__ offs,
    const int* __restrict__ src, const float* __restrict__ w,
    const float* __restrict__ dis, const float* __restrict__ b1,
    const float* __restrict__ W2, float* __restrict__ H2a, int n) {
    __shared__ float Ws[64 * 32];
    __shared__ float rows[16][68];  // pad 68
    const int tid = threadIdx.x;
    for (int i = tid; i < 64 * 32; i += 256) Ws[i] = W2[i];
    const int t = blockIdx.x * 256 + tid;
    const int node = t >> 4, q = t & 15, nl = tid >> 4;
    float4 acc = make_float4(0.f, 0.f, 0.f, 0.f);
    int p0 = offs[node], p1 = offs[node + 1];
    for (int p = p0; p < p1; ++p) {
        float ww = w[p];
        float4 hv = *(const float4*)(h + (size_t)src[p] * 64 + q * 4);
        acc.x = fmaf(ww, hv.x, acc.x);
        acc.y = fmaf(ww, hv.y, acc.y);
        acc.z = fmaf(ww, hv.z, acc.z);
        acc.w = fmaf(ww, hv.w, acc.w);
    }
    float d = dis[node];
    float ds = d * d;
    float4 hv = *(const float4*)(h + (size_t)node * 64 + q * 4);
    float4 bv = *(const float4*)(b1 + q * 4);
    acc.x = fmaxf(fmaf(ds, hv.x, acc.x) + bv.x, 0.f);
    acc.y = fmaxf(fmaf(ds, hv.y, acc.y) + bv.y, 0.f);
    acc.z = fmaxf(fmaf(ds, hv.z, acc.z) + bv.z, 0.f);
    acc.w = fmaxf(fmaf(ds, hv.w, acc.w) + bv.w, 0.f);
    *(float4*)&rows[nl][q * 4] = acc;
    __syncthreads();
    const int c0 = q * 2;
    float s0 = 0.f, s1 = 0.f;
#pragma unroll
    for (int k = 0; k < 64; ++k) {
        float v = rows[nl][k];
        s0 = fmaf(v, Ws[k * 32 + c0], s0);
        s1 = fmaf(v, Ws[k * 32 + c0 + 1], s1);
    }
    H2a[(size_t)node * 32 + c0] = s0;
    H2a[(size_t)node * 32 + c0 + 1] = s1;
}

// --- fused: H2 = relu(Agg(H2a)+b2) ; H3a = H2 @ W3.  8 thr/node, 32 nodes/blk.
__global__ __launch_bounds__(256) void prop32_gemm3_k(
    const float* __restrict__ h, const int* __restrict__ offs,
    const int* __restrict__ src, const float* __restrict__ w,
    const float* __restrict__ dis, const float* __restrict__ b2,
    const float* __restrict__ W3, float* __restrict__ H3a, int n) {
    __shared__ float Ws[32 * 16];
    __shared__ float rows[32][36];  // pad 36
    const int tid = threadIdx.x;
    for (int i = tid; i < 32 * 16; i += 256) Ws[i] = W3[i];
    const int t = blockIdx.x * 256 + tid;
    const int node = t >> 3, q = t & 7, nl = tid >> 3;
    float4 acc = make_float4(0.f, 0.f, 0.f, 0.f);
    int p0 = offs[node], p1 = offs[node + 1];
    for (int p = p0; p < p1; ++p) {
        float ww = w[p];
        float4 hv = *(const float4*)(h + (size_t)src[p] * 32 + q * 4);
        acc.x = fmaf(ww, hv.x, acc.x);
        acc.y = fmaf(ww, hv.y, acc.y);
        acc.z = fmaf(ww, hv.z, acc.z);
        acc.w = fmaf(ww, hv.w, acc.w);
    }
    float d = dis[node];
    float ds = d * d;
    float4 hv = *(const float4*)(h + (size_t)node * 32 + q * 4);
    float4 bv = *(const float4*)(b2 + q * 4);
    acc.x = fmaxf(fmaf(ds, hv.x, acc.x) + bv.x, 0.f);
    acc.y = fmaxf(fmaf(ds, hv.y, acc.y) + bv.y, 0.f);
    acc.z = fmaxf(fmaf(ds, hv.z, acc.z) + bv.z, 0.f);
    acc.w = fmaxf(fmaf(ds, hv.w, acc.w) + bv.w, 0.f);
    *(float4*)&rows[nl][q * 4] = acc;
    __syncthreads();
    const int c0 = q * 2;
    float s0 = 0.f, s1 = 0.f;
#pragma unroll
    for (int k = 0; k < 32; ++k) {
        float v = rows[nl][k];
        s0 = fmaf(v, Ws[k * 16 + c0], s0);
        s1 = fmaf(v, Ws[k * 16 + c0 + 1], s1);
    }
    H3a[(size_t)node * 16 + c0] = s0;
    H3a[(size_t)node * 16 + c0 + 1] = s1;
}

// --- final propagate (F=16) + bias + softmax, float4/thread, 4 lanes/node
__global__ void prop_softmax_k(const float* __restrict__ h, const int* __restrict__ offs,
                               const int* __restrict__ src, const float* __restrict__ w,
                               const float* __restrict__ dis, const float* __restrict__ b,
                               float* __restrict__ out, int n) {
    int t = blockIdx.x * blockDim.x + threadIdx.x;
    int node = t >> 2, q = t & 3;
    if (node >= n) return;
    float4 acc = make_float4(0.f, 0.f, 0.f, 0.f);
    int p0 = offs[node], p1 = offs[node + 1];
    for (int p = p0; p < p1; ++p) {
        float ww = w[p];
        float4 hv = *(const float4*)(h + (size_t)src[p] * 16 + q * 4);
        acc.x = fmaf(ww, hv.x, acc.x);
        acc.y = fmaf(ww, hv.y, acc.y);
        acc.z = fmaf(ww, hv.z, acc.z);
        acc.w = fmaf(ww, hv.w, acc.w);
    }
    float d = dis[node];
    float ds = d * d;
    float4 hv = *(const float4*)(h + (size_t)node * 16 + q * 4);
    float4 bv = *(const float4*)(b + q * 4);
    acc.x = fmaf(ds, hv.x, acc.x) + bv.x;
    acc.y = fmaf(ds, hv.y, acc.y) + bv.y;
    acc.z = fmaf(ds, hv.z, acc.z) + bv.z;
    acc.w = fmaf(ds, hv.w, acc.w) + bv.w;
    float m = fmaxf(fmaxf(acc.x, acc.y), fmaxf(acc.z, acc.w));
    m = fmaxf(m, __shfl_xor(m, 1));
    m = fmaxf(m, __shfl_xor(m, 2));
    float4 e;
    e.x = __expf(acc.x - m);
    e.y = __expf(acc.y - m);
    e.z = __expf(acc.z - m);
    e.w = __expf(acc.w - m);
    float s = e.x + e.y + e.z + e.w;
    s += __shfl_xor(s, 1);
    s += __shfl_xor(s, 2);
    float inv = 1.f / s;
    e.x *= inv; e.y *= inv; e.z *= inv; e.w *= inv;
    *(float4*)(out + (size_t)node * 16 + q * 4) = e;
}

extern "C" void kernel_launch(void* const* d_in, const int* in_sizes, int n_in,
                              void* d_out, int out_size, void* d_ws, size_t ws_size,
                              hipStream_t stream) {
    const float* x  = (const float*)d_in[0];
    const int*   ei = (const int*)d_in[1];
    const float* W1 = (const float*)d_in[2];
    const float* b1 = (const float*)d_in[3];
    const float* W2 = (const float*)d_in[4];
    const float* b2 = (const float*)d_in[5];
    const float* W3 = (const float*)d_in[6];
    const float* b3 = (const float*)d_in[7];
    float* out = (float*)d_out;

    const int n = in_sizes[2] / 64;
    const int K = in_sizes[0] / n;
    const int E = in_sizes[1] / 2;
    const int nb = (n + 255) / 256;  // scan blocks (64 for n=16384)

    char* ws = (char*)d_ws;
    size_t off = 0;
    auto alloc = [&](size_t bytes) {
        char* p = ws + off;
        off = (off + bytes + 255) & ~(size_t)255;
        return p;
    };
    int*   flag   = (int*)  alloc(4);
    int*   cnt    = (int*)  alloc((size_t)n * 4);
    int*   cursor = (int*)  alloc((size_t)n * 4);
    int*   offs   = (int*)  alloc((size_t)(n + 1) * 4);
    int*   btot   = (int*)  alloc((size_t)nb * 4);
    float* dis    = (float*)alloc((size_t)n * 4);
    int*   csrs   = (int*)  alloc((size_t)E * 4);
    float* csrw   = (float*)alloc((size_t)E * 4);
    unsigned short* Btw = (unsigned short*)alloc((size_t)2 * 64 * K * 2);
    float* P      = (float*)alloc((size_t)4 * n * 64 * 4);  // partials; plane 0 = H0
    float* H2a    = (float*)alloc((size_t)n * 32 * 4);
    float* H3a    = (float*)alloc((size_t)n * 16 * 4);
    (void)ws_size; (void)n_in; (void)out_size;

    init_prep_k<<<(K * 64 + 255) / 256, 256, 0, stream>>>(ei, flag, cnt, n, W1, Btw, K);
    count_deg_k<<<(E + 255) / 256, 256, 0, stream>>>(ei, E, flag, cnt);
    scan_blk_k<<<nb, 256, 0, stream>>>(cnt, offs, dis, cursor, btot, n);
    scan_add_k<<<nb, 256, 0, stream>>>(offs, btot, n, nb);
    fill_csr_k<<<(E + 255) / 256, 256, 0, stream>>>(ei, E, flag, offs, cursor, dis, csrs, csrw);

    gemm1_mfma_k<<<(n / 128) * 4, 256, 0, stream>>>(x, Btw, P, n, K, K / 4);
    size_t q = (size_t)n * 64 / 4;
    reduce4_k<<<(int)((q + 255) / 256), 256, 0, stream>>>((float4*)P, q);

    prop64_gemm2_k<<<n * 16 / 256, 256, 0, stream>>>(P, offs, csrs, csrw, dis, b1, W2, H2a, n);
    prop32_gemm3_k<<<n * 8 / 256, 256, 0, stream>>>(H2a, offs, csrs, csrw, dis, b2, W3, H3a, n);
    prop_softmax_k<<<n * 4 / 256, 256, 0, stream>>>(H3a, offs, csrs, csrw, dis, b3, out, n);
}

// Round 16
// 365.345 us; speedup vs baseline: 1.4541x; 1.0463x over previous
//
#include <hip/hip_runtime.h>

// ---------------------------------------------------------------------------
// 3-layer GCN (PyG gcn_norm semantics) on MI355X.
// R16 = R13 (best, 368us) with ONE gemm1 change: both __syncthreads replaced
// by lgkm-only barriers (s_waitcnt lgkmcnt(0) + s_barrier). Theory: the full
// __syncthreads conservatively drains vmcnt(0) (loads+stores share vmcnt on
// CDNA), killing the register A-prefetch every K-step. No global stores are
// in flight in the loop, so lgkm-only is semantically sufficient for the
// LDS write->read->overwrite ordering.
// Also keeps R15's fused scan_add (one fewer dispatch).
// ---------------------------------------------------------------------------

typedef __attribute__((ext_vector_type(8))) short bf16x8;
typedef __attribute__((ext_vector_type(4))) float f32x4;
typedef __attribute__((ext_vector_type(4))) float fv4;

__device__ __forceinline__ float4 ldnt4(const float* p) {
    fv4 v = __builtin_nontemporal_load((const fv4*)p);
    return make_float4(v.x, v.y, v.z, v.w);
}
__device__ __forceinline__ void stnt(float* p, float v) {
    __builtin_nontemporal_store(v, p);
}

__device__ __forceinline__ unsigned cvt_pk_bf16(float a, float b) {
    // D[15:0] = bf16_rne(a), D[31:16] = bf16_rne(b)
    unsigned r;
    asm("v_cvt_pk_bf16_f32 %0, %1, %2" : "=v"(r) : "v"(a), "v"(b));
    return r;
}

// LDS-only barrier: no vmcnt drain (in-flight global LOADS keep flying).
__device__ __forceinline__ void lds_barrier() {
    asm volatile("s_waitcnt lgkmcnt(0)" ::: "memory");
    __builtin_amdgcn_s_barrier();
    asm volatile("" ::: "memory");
}

__device__ __forceinline__ unsigned short f2bf_rne(float f) {
    unsigned u = __float_as_uint(f);
    unsigned r = (u + 0x7FFFu + ((u >> 16) & 1u)) >> 16;
    return (unsigned short)r;
}

// --- fused: zero cnt + int64-vs-int32 probe + W1 split/transpose
__global__ void init_prep_k(const int* __restrict__ ei, int* __restrict__ flag,
                            int* __restrict__ cnt, int n,
                            const float* __restrict__ W1,
                            unsigned short* __restrict__ Bt, int K) {
    int t = blockIdx.x * blockDim.x + threadIdx.x;
    if (t < n) cnt[t] = 0;
    if (t == 0) {
        int f = 1;
        for (int i = 0; i < 256; ++i) {
            if (ei[2 * i + 1] != 0) { f = 0; break; }
        }
        *flag = f;
    }
    if (t < K * 64) {
        int nn = t & 63, k = t >> 6;
        float f = W1[(size_t)k * 64 + nn];
        unsigned short hi = f2bf_rne(f);
        float hf = __uint_as_float((unsigned)hi << 16);
        unsigned short lo = f2bf_rne(f - hf);
        Bt[(size_t)nn * K + k] = hi;
        Bt[(size_t)64 * K + (size_t)nn * K + k] = lo;
    }
}

__device__ __forceinline__ int edge_val(const int* __restrict__ ei, long long idx, int f64) {
    return f64 ? ei[2 * idx] : ei[(int)idx];
}

__global__ void count_deg_k(const int* __restrict__ ei, int E, const int* __restrict__ flag,
                            int* __restrict__ cnt) {
    int e = blockIdx.x * blockDim.x + threadIdx.x;
    if (e >= E) return;
    int f = *flag;
    int c = edge_val(ei, (long long)E + e, f);
    atomicAdd(&cnt[c], 1);
}

// --- multi-block scan, phase A: per-block local exclusive scan + totals
//     + dis = rsqrt(deg+1) + cursor = 0.
__global__ void scan_blk_k(const int* __restrict__ cnt, int* __restrict__ offs,
                           float* __restrict__ dis, int* __restrict__ cursor,
                           int* __restrict__ btot, int n) {
    __shared__ int sh[256];
    const int t = threadIdx.x;
    const int idx = blockIdx.x * 256 + t;
    int v = (idx < n) ? cnt[idx] : 0;
    sh[t] = v;
    __syncthreads();
    for (int o = 1; o < 256; o <<= 1) {
        int add = (t >= o) ? sh[t - o] : 0;
        __syncthreads();
        sh[t] += add;
        __syncthreads();
    }
    if (idx < n) {
        offs[idx] = sh[t] - v;  // exclusive local prefix
        cursor[idx] = 0;
        dis[idx] = rsqrtf((float)(v + 1));  // +1: self loop
    }
    if (t == 255) btot[blockIdx.x] = sh[255];
}

// phase B (fused top-scan + add): each block derives its base from btot.
__global__ void scan_add_k(int* __restrict__ offs, const int* __restrict__ btot,
                           int n, int nb) {
    __shared__ int base_sh, tot_sh;
    const int t = threadIdx.x;
    if (t == 0) {
        int base = 0, tot = 0;
        for (int i = 0; i < nb; ++i) {
            int v = btot[i];
            if (i < (int)blockIdx.x) base += v;
            tot += v;
        }
        base_sh = base;
        tot_sh = tot;
    }
    __syncthreads();
    int idx = blockIdx.x * 256 + t;
    if (idx < n) offs[idx] += base_sh;
    if (blockIdx.x == 0 && t == 0) offs[n] = tot_sh;
}

__global__ void fill_csr_k(const int* __restrict__ ei, int E, const int* __restrict__ flag,
                           const int* __restrict__ offs, int* __restrict__ cursor,
                           const float* __restrict__ dis, int* __restrict__ src,
                           float* __restrict__ w) {
    int e = blockIdx.x * blockDim.x + threadIdx.x;
    if (e >= E) return;
    int f = *flag;
    int r = edge_val(ei, (long long)e, f);
    int c = edge_val(ei, (long long)E + e, f);
    int pos = offs[c] + atomicAdd(&cursor[c], 1);
    src[pos] = r;
    w[pos] = dis[r] * dis[c];
}

// --- GEMM1: [n x K] fp32 @ Bt[2][64][K] -> P[kz][n][64], split-bf16 MFMA.
// BM=128, BN=64, BK=32, 256 thr = 4 waves (2m x 2n), wave tile 64x32.
// K-split x4. R13 skeleton; ONLY change: lgkm-only barriers (no vmcnt drain).
__global__ __launch_bounds__(256) void gemm1_mfma_k(
    const float* __restrict__ A, const unsigned short* __restrict__ Bt,
    float* __restrict__ P, int n, int K, int kchunk) {
    __shared__ unsigned short As[2][128][40];  // [hi/lo][row][k], pad 40
    const int tid = threadIdx.x;
    const int lane = tid & 63;
    const int wid = tid >> 6;
    const int wm = wid >> 1, wn = wid & 1;
    const int lrow = lane & 15, lkh = lane >> 4;
    // XCD-grouped swizzle: XCD pair {2y,2y+1} owns K-chunk y -> its 2MB of B
    const int bid = blockIdx.x;
    const int by = (bid & 7) >> 1;
    const int bx = ((bid >> 3) << 1) | (bid & 1);
    const int bm = bx * 128;
    const int k0 = by * kchunk;
    const int iters = kchunk / 32;  // K=16384 /4 /32 = 128

    const unsigned short* Bh = Bt;
    const unsigned short* Bl = Bt + (size_t)64 * K;

    f32x4 acc[4][2] = {};
    float4 st[4];

    auto loadA = [&](int kt) {
#pragma unroll
        for (int i = 0; i < 4; ++i) {
            int v = tid + i * 256;
            int r = v >> 3, c = (v & 7) * 4;
            st[i] = ldnt4(A + (size_t)(bm + r) * K + k0 + kt * 32 + c);
        }
    };

    loadA(0);
    for (int kt = 0; kt < iters; ++kt) {
        // B fragments from global (L2-resident; NOT nt)
        bf16x8 bh[2], bl[2];
#pragma unroll
        for (int nf = 0; nf < 2; ++nf) {
            int brow = wn * 32 + nf * 16 + lrow;
            size_t bo = (size_t)brow * K + k0 + kt * 32 + lkh * 8;
            bh[nf] = *(const bf16x8*)(Bh + bo);
            bl[nf] = *(const bf16x8*)(Bl + bo);
        }
        // convert staged A regs -> hi/lo bf16 -> LDS (cvt_pk)
#pragma unroll
        for (int i = 0; i < 4; ++i) {
            int v = tid + i * 256;
            int r = v >> 3, c = (v & 7) * 4;
            float f0 = st[i].x, f1 = st[i].y, f2 = st[i].z, f3 = st[i].w;
            unsigned h01 = cvt_pk_bf16(f0, f1);
            unsigned h23 = cvt_pk_bf16(f2, f3);
            float r0 = f0 - __uint_as_float(h01 << 16);
            float r1 = f1 - __uint_as_float(h01 & 0xFFFF0000u);
            float r2 = f2 - __uint_as_float(h23 << 16);
            float r3 = f3 - __uint_as_float(h23 & 0xFFFF0000u);
            unsigned l01 = cvt_pk_bf16(r0, r1);
            unsigned l23 = cvt_pk_bf16(r2, r3);
            *(uint2*)&As[0][r][c] = make_uint2(h01, h23);
            *(uint2*)&As[1][r][c] = make_uint2(l01, l23);
        }
        lds_barrier();                      // ds_writes visible; loads keep flying
        if (kt + 1 < iters) loadA(kt + 1);  // prefetch under MFMA
        bf16x8 ah[4], al[4];
#pragma unroll
        for (int mf = 0; mf < 4; ++mf) {
            int row = wm * 64 + mf * 16 + lrow;
            ah[mf] = *(const bf16x8*)&As[0][row][lkh * 8];
            al[mf] = *(const bf16x8*)&As[1][row][lkh * 8];
        }
#pragma unroll
        for (int mf = 0; mf < 4; ++mf)
#pragma unroll
            for (int nf = 0; nf < 2; ++nf) {
                acc[mf][nf] = __builtin_amdgcn_mfma_f32_16x16x32_bf16(ah[mf], bh[nf], acc[mf][nf], 0, 0, 0);
                acc[mf][nf] = __builtin_amdgcn_mfma_f32_16x16x32_bf16(al[mf], bh[nf], acc[mf][nf], 0, 0, 0);
                acc[mf][nf] = __builtin_amdgcn_mfma_f32_16x16x32_bf16(ah[mf], bl[nf], acc[mf][nf], 0, 0, 0);
            }
        lds_barrier();                      // ds_reads done before next overwrite
    }
    // C/D layout: col = lane&15, row = (lane>>4)*4 + reg. NT stores.
    float* out = P + (size_t)by * n * 64;
#pragma unroll
    for (int mf = 0; mf < 4; ++mf)
#pragma unroll
        for (int nf = 0; nf < 2; ++nf)
#pragma unroll
            for (int j = 0; j < 4; ++j) {
                int row = bm + wm * 64 + mf * 16 + lkh * 4 + j;
                int col = wn * 32 + nf * 16 + lrow;
                stnt(out + (size_t)row * 64 + col, acc[mf][nf][j]);
            }
}

__global__ void reduce4_k(float4* __restrict__ p, size_t q) {
    size_t i = (size_t)blockIdx.x * blockDim.x + threadIdx.x;
    if (i >= q) return;
    float4 a = p[i];
#pragma unroll
    for (int z = 1; z < 4; ++z) {
        float4 b = ldnt4((const float*)(p + i + (size_t)z * q));
        a.x += b.x; a.y += b.y; a.z += b.z; a.w += b.w;
    }
    p[i] = a;
}

// --- fused: H1 = relu(Agg(H0)+b1) ; H2a = H1 @ W2.  16 thr/node, 16 nodes/blk.
__global__ __launch_bounds__(256) void prop64_gemm2_k(
    const float* __restrict__ h, const int* __restrict__ offs,
    const int* __restrict__ src, const float* __restrict__ w,
    const float* __restrict__ dis, const float* __restrict__ b1,
    const float* __restrict__ W2, float* __restrict__ H2a, int n) {
    __shared__ float Ws[64 * 32];
    __shared__ float rows[16][68];  // pad 68
    const int tid = threadIdx.x;
    for (int i = tid; i < 64 * 32; i += 256) Ws[i] = W2[i];
    const int t = blockIdx.x * 256 + tid;
    const int node = t >> 4, q = t & 15, nl = tid >> 4;
    float4 acc = make_float4(0.f, 0.f, 0.f, 0.f);
    int p0 = offs[node], p1 = offs[node + 1];
    for (int p = p0; p < p1; ++p) {
        float ww = w[p];
        float4 hv = *(const float4*)(h + (size_t)src[p] * 64 + q * 4);
        acc.x = fmaf(ww, hv.x, acc.x);
        acc.y = fmaf(ww, hv.y, acc.y);
        acc.z = fmaf(ww, hv.z, acc.z);
        acc.w = fmaf(ww, hv.w, acc.w);
    }
    float d = dis[node];
    float ds = d * d;
    float4 hv = *(const float4*)(h + (size_t)node * 64 + q * 4);
    float4 bv = *(const float4*)(b1 + q * 4);
    acc.x = fmaxf(fmaf(ds, hv.x, acc.x) + bv.x, 0.f);
    acc.y = fmaxf(fmaf(ds, hv.y, acc.y) + bv.y, 0.f);
    acc.z = fmaxf(fmaf(ds, hv.z, acc.z) + bv.z, 0.f);
    acc.w = fmaxf(fmaf(ds, hv.w, acc.w) + bv.w, 0.f);
    *(float4*)&rows[nl][q * 4] = acc;
    __syncthreads();
    const int c0 = q * 2;
    float s0 = 0.f, s1 = 0.f;
#pragma unroll
    for (int k = 0; k < 64; ++k) {
        float v = rows[nl][k];
        s0 = fmaf(v, Ws[k * 32 + c0], s0);
        s1 = fmaf(v, Ws[k * 32 + c0 + 1], s1);
    }
    H2a[(size_t)node * 32 + c0] = s0;
    H2a[(size_t)node * 32 + c0 + 1] = s1;
}

// --- fused: H2 = relu(Agg(H2a)+b2) ; H3a = H2 @ W3.  8 thr/node, 32 nodes/blk.
__global__ __launch_bounds__(256) void prop32_gemm3_k(
    const float* __restrict__ h, const int* __restrict__ offs,
    const int* __restrict__ src, const float* __restrict__ w,
    const float* __restrict__ dis, const float* __restrict__ b2,
    const float* __restrict__ W3, float* __restrict__ H3a, int n) {
    __shared__ float Ws[32 * 16];
    __shared__ float rows[32][36];  // pad 36
    const int tid = threadIdx.x;
    for (int i = tid; i < 32 * 16; i += 256) Ws[i] = W3[i];
    const int t = blockIdx.x * 256 + tid;
    const int node = t >> 3, q = t & 7, nl = tid >> 3;
    float4 acc = make_float4(0.f, 0.f, 0.f, 0.f);
    int p0 = offs[node], p1 = offs[node + 1];
    for (int p = p0; p < p1; ++p) {
        float ww = w[p];
        float4 hv = *(const float4*)(h + (size_t)src[p] * 32 + q * 4);
        acc.x = fmaf(ww, hv.x, acc.x);
        acc.y = fmaf(ww, hv.y, acc.y);
        acc.z = fmaf(ww, hv.z, acc.z);
        acc.w = fmaf(ww, hv.w, acc.w);
    }
    float d = dis[node];
    float ds = d * d;
    float4 hv = *(const float4*)(h + (size_t)node * 32 + q * 4);
    float4 bv = *(const float4*)(b2 + q * 4);
    acc.x = fmaxf(fmaf(ds, hv.x, acc.x) + bv.x, 0.f);
    acc.y = fmaxf(fmaf(ds, hv.y, acc.y) + bv.y, 0.f);
    acc.z = fmaxf(fmaf(ds, hv.z, acc.z) + bv.z, 0.f);
    acc.w = fmaxf(fmaf(ds, hv.w, acc.w) + bv.w, 0.f);
    *(float4*)&rows[nl][q * 4] = acc;
    __syncthreads();
    const int c0 = q * 2;
    float s0 = 0.f, s1 = 0.f;
#pragma unroll
    for (int k = 0; k < 32; ++k) {
        float v = rows[nl][k];
        s0 = fmaf(v, Ws[k * 16 + c0], s0);
        s1 = fmaf(v, Ws[k * 16 + c0 + 1], s1);
    }
    H3a[(size_t)node * 16 + c0] = s0;
    H3a[(size_t)node * 16 + c0 + 1] = s1;
}

// --- final propagate (F=16) + bias + softmax, float4/thread, 4 lanes/node
__global__ void prop_softmax_k(const float* __restrict__ h, const int* __restrict__ offs,
                               const int* __restrict__ src, const float* __restrict__ w,
                               const float* __restrict__ dis, const float* __restrict__ b,
                               float* __restrict__ out, int n) {
    int t = blockIdx.x * blockDim.x + threadIdx.x;
    int node = t >> 2, q = t & 3;
    if (node >= n) return;
    float4 acc = make_float4(0.f, 0.f, 0.f, 0.f);
    int p0 = offs[node], p1 = offs[node + 1];
    for (int p = p0; p < p1; ++p) {
        float ww = w[p];
        float4 hv = *(const float4*)(h + (size_t)src[p] * 16 + q * 4);
        acc.x = fmaf(ww, hv.x, acc.x);
        acc.y = fmaf(ww, hv.y, acc.y);
        acc.z = fmaf(ww, hv.z, acc.z);
        acc.w = fmaf(ww, hv.w, acc.w);
    }
    float d = dis[node];
    float ds = d * d;
    float4 hv = *(const float4*)(h + (size_t)node * 16 + q * 4);
    float4 bv = *(const float4*)(b + q * 4);
    acc.x = fmaf(ds, hv.x, acc.x) + bv.x;
    acc.y = fmaf(ds, hv.y, acc.y) + bv.y;
    acc.z = fmaf(ds, hv.z, acc.z) + bv.z;
    acc.w = fmaf(ds, hv.w, acc.w) + bv.w;
    float m = fmaxf(fmaxf(acc.x, acc.y), fmaxf(acc.z, acc.w));
    m = fmaxf(m, __shfl_xor(m, 1));
    m = fmaxf(m, __shfl_xor(m, 2));
    float4 e;
    e.x = __expf(acc.x - m);
    e.y = __expf(acc.y - m);
    e.z = __expf(acc.z - m);
    e.w = __expf(acc.w - m);
    float s = e.x + e.y + e.z + e.w;
    s += __shfl_xor(s, 1);
    s += __shfl_xor(s, 2);
    float inv = 1.f / s;
    e.x *= inv; e.y *= inv; e.z *= inv; e.w *= inv;
    *(float4*)(out + (size_t)node * 16 + q * 4) = e;
}

extern "C" void kernel_launch(void* const* d_in, const int* in_sizes, int n_in,
                              void* d_out, int out_size, void* d_ws, size_t ws_size,
                              hipStream_t stream) {
    const float* x  = (const float*)d_in[0];
    const int*   ei = (const int*)d_in[1];
    const float* W1 = (const float*)d_in[2];
    const float* b1 = (const float*)d_in[3];
    const float* W2 = (const float*)d_in[4];
    const float* b2 = (const float*)d_in[5];
    const float* W3 = (const float*)d_in[6];
    const float* b3 = (const float*)d_in[7];
    float* out = (float*)d_out;

    const int n = in_sizes[2] / 64;
    const int K = in_sizes[0] / n;
    const int E = in_sizes[1] / 2;
    const int nb = (n + 255) / 256;  // scan blocks (64 for n=16384)

    char* ws = (char*)d_ws;
    size_t off = 0;
    auto alloc = [&](size_t bytes) {
        char* p = ws + off;
        off = (off + bytes + 255) & ~(size_t)255;
        return p;
    };
    int*   flag   = (int*)  alloc(4);
    int*   cnt    = (int*)  alloc((size_t)n * 4);
    int*   cursor = (int*)  alloc((size_t)n * 4);
    int*   offs   = (int*)  alloc((size_t)(n + 1) * 4);
    int*   btot   = (int*)  alloc((size_t)nb * 4);
    float* dis    = (float*)alloc((size_t)n * 4);
    int*   csrs   = (int*)  alloc((size_t)E * 4);
    float* csrw   = (float*)alloc((size_t)E * 4);
    unsigned short* Btw = (unsigned short*)alloc((size_t)2 * 64 * K * 2);
    float* P      = (float*)alloc((size_t)4 * n * 64 * 4);  // partials; plane 0 = H0
    float* H2a    = (float*)alloc((size_t)n * 32 * 4);
    float* H3a    = (float*)alloc((size_t)n * 16 * 4);
    (void)ws_size; (void)n_in; (void)out_size;

    init_prep_k<<<(K * 64 + 255) / 256, 256, 0, stream>>>(ei, flag, cnt, n, W1, Btw, K);
    count_deg_k<<<(E + 255) / 256, 256, 0, stream>>>(ei, E, flag, cnt);
    scan_blk_k<<<nb, 256, 0, stream>>>(cnt, offs, dis, cursor, btot, n);
    scan_add_k<<<nb, 256, 0, stream>>>(offs, btot, n, nb);
    fill_csr_k<<<(E + 255) / 256, 256, 0, stream>>>(ei, E, flag, offs, cursor, dis, csrs, csrw);

    gemm1_mfma_k<<<(n / 128) * 4, 256, 0, stream>>>(x, Btw, P, n, K, K / 4);
    size_t q = (size_t)n * 64 / 4;
    reduce4_k<<<(int)((q + 255) / 256), 256, 0, stream>>>((float4*)P, q);

    prop64_gemm2_k<<<n * 16 / 256, 256, 0, stream>>>(P, offs, csrs, csrw, dis, b1, W2, H2a, n);
    prop32_gemm3_k<<<n * 8 / 256, 256, 0, stream>>>(H2a, offs, csrs, csrw, dis, b2, W3, H3a, n);
    prop_softmax_k<<<n * 4 / 256, 256, 0, stream>>>(H3a, offs, csrs, csrw, dis, b3, out, n);
}